// Round 1
// 1840.655 us; speedup vs baseline: 1.3345x; 1.3345x over previous
//
#include <hip/hip_runtime.h>
#include <cstddef>

// L=8, N=16384, K=16, D_IN=D_OUT=256
#define NL 8
#define NN 16384
#define KC 16
#define DD 256

typedef __bf16 bf16x8 __attribute__((ext_vector_type(8)));
typedef __bf16 bf16x4 __attribute__((ext_vector_type(4)));
typedef float f32x4 __attribute__((ext_vector_type(4)));

__device__ __forceinline__ float sigf(float x) { return 1.0f / (1.0f + expf(-x)); }

// async global->LDS, 16B per lane. LDS dest = wave-uniform base + lane*16.
__device__ __forceinline__ void glds16(const void* g, void* l) {
  __builtin_amdgcn_global_load_lds(
      (const __attribute__((address_space(1))) void*)g,
      (__attribute__((address_space(3))) void*)l, 16, 0, 0);
}

// Build pre-transposed bf16x3 weight panels, virtual-k = [hi(0:256) | hi(256:512) | lo(512:768)]
// pairing with A k-blocks [hi, lo, hi] -> A_hi*B_hi + A_lo*B_hi + A_hi*B_lo.
// WcatT: [1024][768] (W_w cols), UfT: [256][768] (U_f cols), UiuoT: [768][768] (U_iuo cols)
__global__ __launch_bounds__(256) void convert_weights(
    const float* __restrict__ W_w,   // [256,1024]
    const float* __restrict__ U_f,   // [256,256]
    const float* __restrict__ U_iuo, // [256,768]
    __bf16* __restrict__ WcatT,
    __bf16* __restrict__ UfT,
    __bf16* __restrict__ UiuoT) {
  const int b = blockIdx.x;
  const int k = threadIdx.x;
  float w;
  __bf16* dst;
  if (b < 1024) {
    const int n = b;
    w = W_w[k * 1024 + n];
    dst = WcatT + (size_t)n * 768;
  } else if (b < 1280) {
    const int n = b - 1024;
    w = U_f[k * 256 + n];
    dst = UfT + (size_t)n * 768;
  } else {
    const int n = b - 1280;
    w = U_iuo[k * 768 + n];
    dst = UiuoT + (size_t)n * 768;
  }
  const __bf16 hi = (__bf16)w;
  const __bf16 lo = (__bf16)(w - (float)hi);
  dst[k] = hi;
  dst[256 + k] = hi;
  dst[512 + k] = lo;
}

// fp32 -> (hi, lo) bf16 split, elementwise
__global__ __launch_bounds__(256) void convert_split(
    const float* __restrict__ src, __bf16* __restrict__ hi_out, __bf16* __restrict__ lo_out) {
  const size_t i = (size_t)blockIdx.x * 256 + threadIdx.x;
  const float v = src[i];
  const __bf16 hi = (__bf16)v;
  hi_out[i] = hi;
  lo_out[i] = (__bf16)(v - (float)hi);
}

// C[M,N] = splitfp32(A) @ B (+bias), bf16x3 MFMA emulation.
// A_hi/A_lo: [M,256] bf16 row-major. BT: [N][768] bf16 catT panel.
// grid (N/128, M/128), 256 threads, 128x128 tile, global_load_lds staging.
__global__ __launch_bounds__(256) void gemm_mfma(
    const __bf16* __restrict__ A_hi, const __bf16* __restrict__ A_lo,
    const __bf16* __restrict__ BT, const float* __restrict__ bias,
    float* __restrict__ C, int N) {
  __shared__ __align__(16) __bf16 As[128][32];
  __shared__ __align__(16) __bf16 Bs[128][32];
  const int tid = threadIdx.x;
  const int bm = blockIdx.y << 7;
  const int bn = blockIdx.x << 7;
  const int w = tid >> 6;
  const int lane = tid & 63;
  const int r = lane & 15;      // fragment row
  const int q = lane >> 4;      // k-quad
  const int wm = (w & 1) << 6;
  const int wn = (w >> 1) << 6;
  const int sr0 = tid >> 2;     // staging row 0..63
  const int sk = (tid & 3) << 3;
  // byte offset of As[sr0][sk] == tid*16 == w*1024 + lane*16  (wave-uniform base + lane*16)
  char* AsB = (char*)(&As[0][0]) + w * 1024;
  char* BsB = (char*)(&Bs[0][0]) + w * 1024;

  f32x4 acc[4][4];
#pragma unroll
  for (int i = 0; i < 4; ++i)
#pragma unroll
    for (int j = 0; j < 4; ++j) {
      acc[i][j][0] = 0.f; acc[i][j][1] = 0.f; acc[i][j][2] = 0.f; acc[i][j][3] = 0.f;
    }

  for (int kb = 0; kb < 24; ++kb) {
    const __bf16* Asrc;
    int koff;
    if (kb < 8)       { Asrc = A_hi; koff = kb << 5; }
    else if (kb < 16) { Asrc = A_lo; koff = (kb - 8) << 5; }
    else              { Asrc = A_hi; koff = (kb - 16) << 5; }
    const __bf16* ga = Asrc + (size_t)(bm + sr0) * 256 + koff + sk;
    const __bf16* gb = BT + (size_t)(bn + sr0) * 768 + (kb << 5) + sk;
    __syncthreads();  // previous iter's LDS reads done
    glds16(ga, AsB);
    glds16(ga + (size_t)64 * 256, AsB + 4096);
    glds16(gb, BsB);
    glds16(gb + (size_t)64 * 768, BsB + 4096);
    __syncthreads();  // vmcnt(0) drain -> tile ready
    bf16x8 af[4], bfr[4];
#pragma unroll
    for (int i = 0; i < 4; ++i) af[i] = *(const bf16x8*)(&As[wm + i * 16 + r][q << 3]);
#pragma unroll
    for (int j = 0; j < 4; ++j) bfr[j] = *(const bf16x8*)(&Bs[wn + j * 16 + r][q << 3]);
#pragma unroll
    for (int i = 0; i < 4; ++i)
#pragma unroll
      for (int j = 0; j < 4; ++j)
        acc[i][j] = __builtin_amdgcn_mfma_f32_16x16x32_bf16(af[i], bfr[j], acc[i][j], 0, 0, 0);
  }

  float bv[4] = {0.f, 0.f, 0.f, 0.f};
  if (bias) {
#pragma unroll
    for (int j = 0; j < 4; ++j) bv[j] = bias[bn + wn + j * 16 + r];
  }
#pragma unroll
  for (int i = 0; i < 4; ++i) {
    const int row0 = bm + wm + i * 16 + (q << 2);
#pragma unroll
    for (int j = 0; j < 4; ++j) {
      const int col = bn + wn + j * 16 + r;
#pragma unroll
      for (int t2 = 0; t2 < 4; ++t2)
        C[(size_t)(row0 + t2) * N + col] = acc[i][j][t2] + bv[j];
    }
  }
}

// Gather phase: per edge read only Gf row-chunk (forget gate pre-act), h row-chunk, c row-chunk.
// f_out[n,d] = sum_j sig(Wf[n,d]+Gf[j,d])*c[j,d];  hs = sum_j h[j,:] -> bf16 hi/lo split.
// XCD-chunked: chunk = blockIdx&7 handles dims [chunk*32, chunk*32+32) (=128B, one line),
// so each XCD's gather working set is (16+16+16)/8 = 6MB vs its 4MB L2 (round-robin block->XCD).
// 256 threads = 4 waves; wave = 8 nodes x 8 lanes; lane = 4 dims (float4).
__global__ __launch_bounds__(256) void gather_children(
    const float* __restrict__ Wx,      // [NN,1024], cols 0..255 = Wf
    const int* __restrict__ idx,       // [NN,16]
    const float* __restrict__ Gf,      // [NN,256]
    const float* __restrict__ h_prev,  // [NN,256]
    const float* __restrict__ c_prev,  // [NN,256]
    float* __restrict__ f_out,         // [NN,256]
    __bf16* __restrict__ hs_hi,        // [NN,256]
    __bf16* __restrict__ hs_lo) {
  const int tid = threadIdx.x;
  const int wv = tid >> 6;
  const int lane = tid & 63;
  const int grp = lane >> 3;                        // node within wave
  const int sub = lane & 7;                         // float4 slot within chunk
  const int n = ((blockIdx.x >> 3) << 5) + (wv << 3) + grp;
  const int d = ((blockIdx.x & 7) << 5) + (sub << 2);
  const int gb = lane & 56;                         // group base lane
  const int jk1 = idx[n * KC + sub];                // children 0..7 (one per lane of group)
  const int jk2 = idx[n * KC + 8 + sub];            // children 8..15
  const f32x4 wf = *(const f32x4*)(Wx + (size_t)n * 1024 + d);
  f32x4 f = {0.f, 0.f, 0.f, 0.f};
  f32x4 hs = {0.f, 0.f, 0.f, 0.f};
#pragma unroll
  for (int k = 0; k < KC; ++k) {
    const int j = (k < 8) ? __shfl(jk1, gb + k) : __shfl(jk2, gb + (k - 8));
    const float m = (j > 0) ? 1.0f : 0.0f;          // -1 masked, 0 = zero init row
    const size_t off = (size_t)((j > 0) ? (j - 1) : 0) * 256 + d;
    const f32x4 gv = *(const f32x4*)(Gf + off);
    const f32x4 hv = *(const f32x4*)(h_prev + off);
    const f32x4 cv = *(const f32x4*)(c_prev + off);
#pragma unroll
    for (int t = 0; t < 4; ++t) {
      f[t] += sigf(wf[t] + gv[t]) * (cv[t] * m);
      hs[t] += hv[t] * m;
    }
  }
  *(f32x4*)(f_out + (size_t)n * DD + d) = f;
  bf16x4 hh, hl;
#pragma unroll
  for (int t = 0; t < 4; ++t) {
    const __bf16 hi = (__bf16)hs[t];
    hh[t] = hi;
    hl[t] = (__bf16)(hs[t] - (float)hi);
  }
  *(bf16x4*)(hs_hi + (size_t)n * DD + d) = hh;
  *(bf16x4*)(hs_lo + (size_t)n * DD + d) = hl;
}

// Streaming epilogue: gates from Wx (i,u,o parts) + iuo GEMM output + f.
// 256 threads = 4 waves; wave = 1 node; lane = 4 dims.
__global__ __launch_bounds__(256) void node_finish(
    const float* __restrict__ Wx,      // [NN,1024]
    const float* __restrict__ iuo,     // [NN,768] (null at t=0)
    const float* __restrict__ f_in,    // [NN,256] (null at t=0)
    float* __restrict__ h_out, float* __restrict__ c_out,
    __bf16* __restrict__ h_hi, __bf16* __restrict__ h_lo,
    int has_prev) {
  const int tid = threadIdx.x;
  const int wv = tid >> 6;
  const int lane = tid & 63;
  const int n = (blockIdx.x << 2) + wv;
  const int d4 = lane << 2;
  const float* wrow = Wx + (size_t)n * 1024;
  const f32x4 wi = *(const f32x4*)(wrow + 256 + d4);
  const f32x4 wu = *(const f32x4*)(wrow + 512 + d4);
  const f32x4 wo = *(const f32x4*)(wrow + 768 + d4);
  f32x4 gi = {0.f, 0.f, 0.f, 0.f}, gu = {0.f, 0.f, 0.f, 0.f},
        go = {0.f, 0.f, 0.f, 0.f}, fv = {0.f, 0.f, 0.f, 0.f};
  if (has_prev) {
    const float* grow = iuo + (size_t)n * 768;
    gi = *(const f32x4*)(grow + d4);
    gu = *(const f32x4*)(grow + 256 + d4);
    go = *(const f32x4*)(grow + 512 + d4);
    fv = *(const f32x4*)(f_in + (size_t)n * DD + d4);
  }
  f32x4 hv, cv;
  bf16x4 hh, hl;
#pragma unroll
  for (int t = 0; t < 4; ++t) {
    const float iv = sigf(wi[t] + gi[t]);
    const float uv = tanhf(wu[t] + gu[t]);
    const float ov = sigf(wo[t] + go[t]);
    const float nc = iv * uv + fv[t];
    const float nh = ov * tanhf(nc);
    cv[t] = nc;
    hv[t] = nh;
    const __bf16 hi = (__bf16)nh;
    hh[t] = hi;
    hl[t] = (__bf16)(nh - (float)hi);
  }
  *(f32x4*)(h_out + (size_t)n * DD + d4) = hv;
  *(f32x4*)(c_out + (size_t)n * DD + d4) = cv;
  *(bf16x4*)(h_hi + (size_t)n * DD + d4) = hh;
  *(bf16x4*)(h_lo + (size_t)n * DD + d4) = hl;
}

extern "C" void kernel_launch(void* const* d_in, const int* in_sizes, int n_in,
                              void* d_out, int out_size, void* d_ws, size_t ws_size,
                              hipStream_t stream) {
  const float* tensor  = (const float*)d_in[0];  // [L,N,256]
  const int*   indices = (const int*)  d_in[1];  // [L,N,16]
  const float* W_w     = (const float*)d_in[2];  // [256,1024]
  const float* W_b     = (const float*)d_in[3];  // [1024]
  const float* U_f     = (const float*)d_in[4];  // [256,256]
  const float* U_iuo   = (const float*)d_in[5];  // [256,768]

  float* out   = (float*)d_out;
  float* res_h = out;                            // [L,N,256]
  float* res_c = out + (size_t)NL * NN * DD;     // [L,N,256]

  // workspace carve (163MB total, same footprint as proven baseline; 16B aligned)
  char* p = (char*)d_ws;
  __bf16* WcatT = (__bf16*)p; p += (size_t)1024 * 768 * 2;   // 1.5MB
  __bf16* UfT   = (__bf16*)p; p += (size_t)256 * 768 * 2;    // 0.375MB
  __bf16* UiuoT = (__bf16*)p; p += (size_t)768 * 768 * 2;    // 1.125MB
  __bf16* x_hi  = (__bf16*)p; p += (size_t)NN * 256 * 2;     // 8MB
  __bf16* x_lo  = (__bf16*)p; p += (size_t)NN * 256 * 2;     // 8MB
  __bf16* h_hi  = (__bf16*)p; p += (size_t)NN * 256 * 2;     // 8MB
  __bf16* h_lo  = (__bf16*)p; p += (size_t)NN * 256 * 2;     // 8MB
  __bf16* hs_hi = (__bf16*)p; p += (size_t)NN * 256 * 2;     // 8MB
  __bf16* hs_lo = (__bf16*)p; p += (size_t)NN * 256 * 2;     // 8MB
  float*  Wx    = (float*)p;  p += (size_t)NN * 1024 * 4;    // 64MB
  float*  iuo   = (float*)p;  p += (size_t)NN * 768 * 4;     // 48MB
  // aliases (lifetimes disjoint on the serial stream):
  float* Gf    = iuo;          // Gf[16MB] dead before iuo GEMM writes
  float* f_buf = (float*)x_hi; // f[16MB] written after Wx GEMM consumed x_hi/x_lo

  convert_weights<<<2048, 256, 0, stream>>>(W_w, U_f, U_iuo, WcatT, UfT, UiuoT);

  for (int t = 0; t < NL; ++t) {
    const float* x = tensor + (size_t)t * NN * 256;
    const int has_prev = (t > 0) ? 1 : 0;
    if (has_prev) {
      // Gf = h_prev @ U_f  (h_hi/h_lo written by previous level's node_finish)
      gemm_mfma<<<dim3(2, 128), 256, 0, stream>>>(h_hi, h_lo, UfT, nullptr, Gf, 256);
    }
    convert_split<<<NN, 256, 0, stream>>>(x, x_hi, x_lo);
    gemm_mfma<<<dim3(8, 128), 256, 0, stream>>>(x_hi, x_lo, WcatT, W_b, Wx, 1024);
    if (has_prev) {
      gather_children<<<4096, 256, 0, stream>>>(
          Wx, indices + (size_t)t * NN * KC, Gf,
          res_h + (size_t)(t - 1) * NN * DD, res_c + (size_t)(t - 1) * NN * DD,
          f_buf, hs_hi, hs_lo);
      // iuo = h_sum @ U_iuo
      gemm_mfma<<<dim3(6, 128), 256, 0, stream>>>(hs_hi, hs_lo, UiuoT, nullptr, iuo, 768);
    }
    node_finish<<<4096, 256, 0, stream>>>(
        Wx, has_prev ? iuo : nullptr, has_prev ? f_buf : nullptr,
        res_h + (size_t)t * NN * DD, res_c + (size_t)t * NN * DD,
        h_hi, h_lo, has_prev);
  }
}